// Round 1
// 248.037 us; speedup vs baseline: 1.0139x; 1.0139x over previous
//
#include <hip/hip_runtime.h>
#include <stdint.h>

// B=8, S=4096, H=16, E=64, s=64; rfft len 127, irfft len 126.
#define OUT2_OFF 33554432ull

typedef float v4f __attribute__((ext_vector_type(4)));

__device__ __forceinline__ v4f shflx4(v4f s, int m) {
    v4f r;
    r.x = __shfl_xor(s.x, m);
    r.y = __shfl_xor(s.y, m);
    r.z = __shfl_xor(s.z, m);
    r.w = __shfl_xor(s.w, m);
    return r;
}

// Reduce 8 per-row partials A[0..7] across lane bits 1..3 of the 16-lane
// group: afterwards lane rs holds the 8-lane partial (over lanes sharing
// rs bit 0) of row k = 4*rs_1 + 2*rs_2 + rs_3.
__device__ __forceinline__ v4f reduce8(v4f* A, int rs) {
#pragma unroll
    for (int k = 0; k < 4; ++k) {
        v4f s = (rs & 2) ? A[k] : A[k + 4];
        v4f r = shflx4(s, 2);
        A[k] = ((rs & 2) ? A[k + 4] : A[k]) + r;
    }
#pragma unroll
    for (int k = 0; k < 2; ++k) {
        v4f s = (rs & 4) ? A[k] : A[k + 2];
        v4f r = shflx4(s, 4);
        A[k] = ((rs & 4) ? A[k + 2] : A[k]) + r;
    }
    v4f s = (rs & 8) ? A[0] : A[1];
    v4f r = shflx4(s, 8);
    return ((rs & 8) ? A[1] : A[0]) + r;
}

// ---------------------------------------------------------------------------
// Kernel 1 (fused dispatch):
//  bid < 512 : reduce path. Block (bh, ig): 16 i-rows. Barrier-free.
//    Row sums now use a DEFERRED reduce-scatter: capture per-row lane
//    partials in A[8] (two groups of 8 rows), reduce each group with 28
//    shfl, then one cross-parity shfl pairs the groups so ALL 64 lanes
//    store one us row as v4f. 60 shfl/thread vs 256 in the butterfly.
//  bid >= 512: prep path (256 blocks): build G[h][t][j] via twiddle tables.
// ---------------------------------------------------------------------------
__global__ __launch_bounds__(256) void fused1_kernel(
        const float* __restrict__ v,      // [8][4096][16][64]
        const float* __restrict__ wgt,    // [16][127]
        float* __restrict__ us,           // [128][64][64]
        float* __restrict__ vs_part,      // [4][128][64][64]
        float* __restrict__ G) {          // [16][64][64]
    const int bid = blockIdx.x;
    const int tid = threadIdx.x;

    if (bid < 512) {
        const int ig = bid & 3, bh = bid >> 2;
        const int b = bh >> 4, h = bh & 15;
        const int w = tid >> 6, lane = tid & 63;
        const int rs = lane & 15;            // j-sub within wave
        const int q  = 4 * w + (lane >> 4);  // e-chunk (float4)

        const v4f* v4 = (const v4f*)v;
        const size_t base4 = (size_t)b * 1048576 + (size_t)h * 16 + q;

        v4f vsacc[4];
#pragma unroll
        for (int a = 0; a < 4; ++a) vsacc[a] = (v4f)0.f;
        v4f A[8], cur[4], nxt[4], R0;

#pragma unroll
        for (int jh = 0; jh < 4; ++jh)
            cur[jh] = __builtin_nontemporal_load(
                v4 + base4 + (size_t)(ig * 1024 + jh * 16 + rs) * 256);

#pragma unroll
        for (int il = 0; il < 16; ++il) {
            const int i = ig * 16 + il;
            if (il < 15) {
#pragma unroll
                for (int jh = 0; jh < 4; ++jh)
                    nxt[jh] = __builtin_nontemporal_load(
                        v4 + base4 + (size_t)((i + 1) * 64 + jh * 16 + rs) * 256);
            }
            v4f p = (cur[0] + cur[1]) + (cur[2] + cur[3]);
#pragma unroll
            for (int jh = 0; jh < 4; ++jh) vsacc[jh] += cur[jh];
            A[il & 7] = p;
            if (il == 7) R0 = reduce8(A, rs);
#pragma unroll
            for (int jh = 0; jh < 4; ++jh) cur[jh] = nxt[jh];
        }
        v4f R1 = reduce8(A, rs);
        {
            // cross-parity: even lanes complete group 0, odd lanes group 1.
            v4f s = (rs & 1) ? R0 : R1;
            v4f r = shflx4(s, 1);
            v4f res = ((rs & 1) ? R1 : R0) + r;
            const int ir = ((rs & 1) << 3) | (((rs >> 1) & 1) << 2) |
                           (((rs >> 2) & 1) << 1) | ((rs >> 3) & 1);
            *(v4f*)(us + ((size_t)bh * 64 + ig * 16 + ir) * 64 + q * 4) = res;
        }
#pragma unroll
        for (int jh = 0; jh < 4; ++jh) {
            const int j = jh * 16 + rs;
            *(v4f*)(vs_part + (((size_t)ig * 128 + bh) * 64 + j) * 64 + q * 4) =
                vsacc[jh];
        }
    } else {
        // ---- prep path: G[h][t][j] ----
        const int pb = bid - 512;
        const int h = pb >> 4, tq = pb & 15;
        __shared__ float zl[127];
        __shared__ float c127t[127], s127t[127];
        __shared__ float c126t[126], s126t[126];
        __shared__ float ZA[64], ZB[64];
        const float w127 = 6.28318530717958647692f / 127.0f;
        const float w126 = 6.28318530717958647692f / 126.0f;
        if (tid < 127) {
            zl[tid] = wgt[h * 127 + tid];
            float sv, cv; __sincosf((float)tid * w127, &sv, &cv);
            c127t[tid] = cv; s127t[tid] = sv;
        } else if (tid >= 128 && tid < 254) {
            const int m = tid - 128;
            float sv, cv; __sincosf((float)m * w126, &sv, &cv);
            c126t[m] = cv; s126t[m] = sv;
        }
        __syncthreads();
        if (tid < 64) {
            const int k = tid;
            float a = 0.f, bq = 0.f;
            int r = 0;
            for (int m = 0; m < 127; ++m) {
                a  += zl[m] * c127t[r];
                bq -= zl[m] * s127t[r];
                r += k; if (r >= 127) r -= 127;
            }
            ZA[k] = a; ZB[k] = bq;
        }
        __syncthreads();
        const int t = tq * 4 + (tid >> 6);
        const int j = tid & 63;
        const int jj = 63 + j;
        float acc = ZA[0];
        int rb = t, ra = jj;                       // k = 1 values
        for (int k = 1; k <= 62; ++k) {
            const float cA = c126t[rb], sA = s126t[rb];
            const float cB = c127t[ra], sB = s127t[ra];
            const float cAB = cA * cB + sA * sB;   // cos(A-B)
            const float sAB = sA * cB - cA * sB;   // sin(A-B)
            acc += 2.f * (ZA[k] * cAB - ZB[k] * sAB);
            rb += t;  if (rb >= 126) rb -= 126;
            ra += jj; if (ra >= 127) ra -= 127;
        }
        {   // Nyquist of length-126 inverse
            const int rn = (63 * jj) % 127;
            const float term = ZA[63] * c127t[rn] + ZB[63] * s127t[rn];
            acc += (t & 1) ? -term : term;
        }
        G[((size_t)h * 64 + t) * 64 + j] = acc * (1.0f / 126.0f);
    }
}

// ---------------------------------------------------------------------------
// Kernel 2:
//  bid < 512 : block (bh, tq). v4f-staged us/vs(+combine)/G^T into LDS;
//    conv with loop-interchange (unchanged); store phase preloads 4 v4f
//    rxv rows per thread and emits 64 v4f nt stores (1 KB/wave-instr).
//  bid >= 512: 64 tail blocks emit out2 from G and o_ (v4f G reads).
// ---------------------------------------------------------------------------
__global__ __launch_bounds__(256) void convemit_kernel(
        const float* __restrict__ G,
        const float* __restrict__ us,
        const float* __restrict__ vs_part,
        const float* __restrict__ ovec,
        float* __restrict__ out) {
    const int bid = blockIdx.x;
    const int tid = threadIdx.x;

    __shared__ __align__(16) float GlT[64 * 68];     // GlT[j*68 + t] = G[t][j]
    __shared__ __align__(16) float usl[4096];        // [i][e]
    __shared__ __align__(16) float vsl[4096];        // [j][e]
    __shared__ __align__(16) float rxv_l[64 * 68];   // [j][e], stride 68
    __shared__ __align__(16) float rxu_l[16 * 68];   // [il][e]
    __shared__ __align__(16) float zpb[1024];        // tail: [h][n]
    __shared__ __align__(16) float ol[64];

    if (bid < 512) {
        const int bh = bid >> 2, tq = bid & 3;
        const int b = bh >> 4, h = bh & 15;

        const v4f* usg = (const v4f*)(us + (size_t)bh * 4096);
        const v4f* vp0 = (const v4f*)(vs_part + (size_t)bh * 4096);
        const v4f* vp1 = (const v4f*)(vs_part + (size_t)(128 + bh) * 4096);
        const v4f* vp2 = (const v4f*)(vs_part + (size_t)(256 + bh) * 4096);
        const v4f* vp3 = (const v4f*)(vs_part + (size_t)(384 + bh) * 4096);
        const v4f* Gg  = (const v4f*)(G + (size_t)h * 4096);

#pragma unroll
        for (int k = 0; k < 4; ++k) {
            const int vi = k * 256 + tid;       // v4f index
            const int fi = vi * 4;              // float index
            v4f uu = usg[vi];
            *(v4f*)&usl[fi] = uu;
            v4f a = (vp0[vi] + vp1[vi]) + (vp2[vi] + vp3[vi]);
            *(v4f*)&vsl[fi] = a;
            v4f g = Gg[vi];
            const int t = fi >> 6, j0 = fi & 63;
            GlT[(j0 + 0) * 68 + t] = g.x;
            GlT[(j0 + 1) * 68 + t] = g.y;
            GlT[(j0 + 2) * 68 + t] = g.z;
            GlT[(j0 + 3) * 68 + t] = g.w;
        }
        __syncthreads();

        {
            const int tb = tid >> 4;           // 0..15
            const int q  = tid & 15;           // e-chunk (float4)
            const int i_row = tq * 16 + tb;
            const v4f* us4 = (const v4f*)usl;
            const v4f* vs4 = (const v4f*)vsl;

            v4f accV[4];
#pragma unroll
            for (int r = 0; r < 4; ++r) accV[r] = (v4f)0.f;
            v4f accU = (v4f)0.f;
#pragma unroll 8
            for (int j = 0; j < 64; ++j) {
                const v4f gv = *(const v4f*)&GlT[j * 68 + tb * 4];
                const float gu = GlT[j * 68 + i_row];
                const v4f vv = vs4[j * 16 + q];
                const v4f uu = us4[j * 16 + q];
                accV[0] += gv.x * vv;
                accV[1] += gv.y * vv;
                accV[2] += gv.z * vv;
                accV[3] += gv.w * vv;
                accU += gu * uu;
            }
#pragma unroll
            for (int r = 0; r < 4; ++r)
                *(v4f*)&rxv_l[(tb * 4 + r) * 68 + q * 4] = accV[r];
            *(v4f*)&rxu_l[tb * 68 + q * 4] = accU;
        }
        __syncthreads();

        // store phase: lane = (jsub 0..3, qq 0..15); each thread covers
        // j = jj*16 + w*4 + jsub (jj=0..3) and e-chunk qq, all 16 il rows.
        const int w = tid >> 6, lane = tid & 63;
        const int jsub = lane >> 4, qq = lane & 15;
        v4f rv4[4];
#pragma unroll
        for (int jj = 0; jj < 4; ++jj)
            rv4[jj] = *(const v4f*)&rxv_l[(jj * 16 + w * 4 + jsub) * 68 + qq * 4];
        const size_t obase =
            (((size_t)b * 4096 + tq * 1024) * 16 + h) * 64 + qq * 4;
        for (int il = 0; il < 16; ++il) {
            const v4f ru = *(const v4f*)&rxu_l[il * 68 + qq * 4];
#pragma unroll
            for (int jj = 0; jj < 4; ++jj) {
                const int j = jj * 16 + w * 4 + jsub;
                __builtin_nontemporal_store(rv4[jj] + ru,
                    (v4f*)(out + obase + (size_t)(il * 64 + j) * 1024));
            }
        }
    } else {
        const int bz = bid - 512;          // 0..63: the t>>6 coordinate
        if (tid < 64) ol[tid] = ovec[tid];
        __syncthreads();
#pragma unroll
        for (int r = 0; r < 4; ++r) {
            const int idx = tid + 256 * r;
            const int h = idx >> 6, n = idx & 63;
            const v4f* G4 = (const v4f*)(G + (size_t)h * 4096 + n * 64);
            v4f acc4 = (v4f)0.f;
#pragma unroll
            for (int jv = 0; jv < 16; ++jv)
                acc4 += (*(const v4f*)&ol[jv * 4]) * G4[jv];
            zpb[idx] = (acc4.x + acc4.y + acc4.z + acc4.w) * 64.f;  // * s
        }
        __syncthreads();
#pragma unroll
        for (int r = 0; r < 4; ++r) {
            const int k = tid + 256 * r;
            const int hh = k & 15, c = k >> 4;
            out[OUT2_OFF + ((size_t)(bz * 64 + c)) * 16 + hh] =
                zpb[hh * 64 + c] + zpb[hh * 64 + bz];
        }
    }
}

extern "C" void kernel_launch(void* const* d_in, const int* in_sizes, int n_in,
                              void* d_out, int out_size, void* d_ws, size_t ws_size,
                              hipStream_t stream) {
    const float* v    = (const float*)d_in[0];   // (8,4096,16,64) f32
    const float* wgt  = (const float*)d_in[1];   // (1,16,127) f32
    const float* ovec = (const float*)d_in[2];   // (64,) f32

    float* G       = (float*)d_ws;               // 65536 floats
    float* us      = G + 65536;                  // 524288 floats
    float* vs_part = us + 524288;                // 2097152 floats
    float* out     = (float*)d_out;

    hipLaunchKernelGGL(fused1_kernel,   dim3(512 + 256), dim3(256), 0, stream,
                       v, wgt, us, vs_part, G);
    hipLaunchKernelGGL(convemit_kernel, dim3(512 + 64),  dim3(256), 0, stream,
                       G, us, vs_part, ovec, out);
}

// Round 3
// 240.863 us; speedup vs baseline: 1.0441x; 1.0298x over previous
//
#include <hip/hip_runtime.h>
#include <stdint.h>

// B=8, S=4096, H=16, E=64, s=64; rfft len 127, irfft len 126.
#define OUT2_OFF 33554432ull

typedef float v4f __attribute__((ext_vector_type(4)));

__device__ __forceinline__ v4f shflx4(v4f s, int m) {
    v4f r;
    r.x = __shfl_xor(s.x, m);
    r.y = __shfl_xor(s.y, m);
    r.z = __shfl_xor(s.z, m);
    r.w = __shfl_xor(s.w, m);
    return r;
}

// ---------------------------------------------------------------------------
// Kernel 1 (fused dispatch):
//  bid < 512 : reduce path, block (bh, ig) = 16 i-rows (1024 t-rows).
//    COALESCED lane map: g = tid>>4 picks the t-row (t = ig*1024 + g + 16k),
//    q = tid&15 picks the e-chunk -> each wave instruction reads 4 rows x
//    256 B contiguous (was 16 scattered 64-B segments).
//    vs: j = g + 16*(k&3), accumulated thread-locally (4 v4f), stored direct.
//    us: i = k>>2; per-half (8 i) in-wave reduce-scatter over lane bits 4,5
//    (12 v4f shfl), cross-wave 4-way combine via 16 KiB LDS + 1 barrier.
//  bid >= 512: prep path (256 blocks): build G[h][t][j] via twiddle tables.
// ---------------------------------------------------------------------------
__global__ __launch_bounds__(256) void fused1_kernel(
        const float* __restrict__ v,      // [8][4096][16][64]
        const float* __restrict__ wgt,    // [16][127]
        float* __restrict__ us,           // [128][64][64]
        float* __restrict__ vs_part,      // [4][128][64][64]
        float* __restrict__ G) {          // [16][64][64]
    const int bid = blockIdx.x;
    const int tid = threadIdx.x;

    __shared__ __align__(16) v4f upart[4][16][16];   // [wave][i][q], 16 KiB
    // prep-path tables (separate branch, small)
    __shared__ float zl[127];
    __shared__ float c127t[127], s127t[127];
    __shared__ float c126t[126], s126t[126];
    __shared__ float ZA[64], ZB[64];

    if (bid < 512) {
        const int ig = bid & 3, bh = bid >> 2;
        const int b = bh >> 4, h = bh & 15;
        const int g = tid >> 4;              // row-sub 0..15
        const int q = tid & 15;              // e-chunk (float4)
        const int w = tid >> 6;
        const int lane = tid & 63;
        const int s1 = (lane >> 4) & 1, s2 = (lane >> 5) & 1;

        const v4f* v4 = (const v4f*)v;
        // v4f index: b*1048576 + t*256 + h*16 + q,  t = ig*1024 + g + 16k
        const size_t baseq =
            (size_t)b * 1048576 + (size_t)(ig * 1024 + g) * 256 + h * 16 + q;

        v4f vsacc[4], uacc[8], buf[8];
#pragma unroll
        for (int a = 0; a < 4; ++a) vsacc[a] = (v4f)0.f;
#pragma unroll
        for (int a = 0; a < 8; ++a) uacc[a] = (v4f)0.f;

#pragma unroll
        for (int k0 = 0; k0 < 8; ++k0)
            buf[k0] = __builtin_nontemporal_load(v4 + baseq + (size_t)k0 * 4096);

#pragma unroll
        for (int k = 0; k < 64; ++k) {
            v4f c = buf[k & 7];
            if (k < 56)
                buf[k & 7] = __builtin_nontemporal_load(
                    v4 + baseq + (size_t)(k + 8) * 4096);
            vsacc[k & 3] += c;           // j = g + 16*(k&3)
            uacc[(k >> 2) & 7] += c;     // i = k>>2
            if ((k & 31) == 31) {
                const int h0 = k >> 5;   // half index
                // in-wave reduce-scatter over lane bits 4 (s1) and 5 (s2):
                // result lane holds full 4-group partial of i_loc = m+2*s2+4*s1
                v4f t4[4];
#pragma unroll
                for (int m = 0; m < 4; ++m) {
                    v4f keep = s1 ? uacc[m + 4] : uacc[m];
                    v4f send = s1 ? uacc[m] : uacc[m + 4];
                    t4[m] = keep + shflx4(send, 16);
                }
#pragma unroll
                for (int m = 0; m < 2; ++m) {
                    v4f keep = s2 ? t4[m + 2] : t4[m];
                    v4f send = s2 ? t4[m] : t4[m + 2];
                    v4f r = keep + shflx4(send, 32);
                    upart[w][h0 * 8 + m + 2 * s2 + 4 * s1][q] = r;
                }
#pragma unroll
                for (int m = 0; m < 8; ++m) uacc[m] = (v4f)0.f;
            }
        }
        // vs stores: thread-local, no sync needed. 4 rows x 256 B per instr.
#pragma unroll
        for (int jh = 0; jh < 4; ++jh)
            *(v4f*)(vs_part + (((size_t)ig * 128 + bh) * 64 + g + 16 * jh) * 64 +
                    q * 4) = vsacc[jh];
        __syncthreads();
        {
            // cross-wave combine: 256 threads <-> 256 (i,q) pairs
            const int i = tid >> 4, q2 = tid & 15;
            v4f ssum = (upart[0][i][q2] + upart[1][i][q2]) +
                       (upart[2][i][q2] + upart[3][i][q2]);
            *(v4f*)(us + ((size_t)bh * 64 + ig * 16 + i) * 64 + q2 * 4) = ssum;
        }
    } else {
        // ---- prep path: G[h][t][j] ----
        const int pb = bid - 512;
        const int h = pb >> 4, tq = pb & 15;
        const float w127 = 6.28318530717958647692f / 127.0f;
        const float w126 = 6.28318530717958647692f / 126.0f;
        if (tid < 127) {
            zl[tid] = wgt[h * 127 + tid];
            float sv, cv; __sincosf((float)tid * w127, &sv, &cv);
            c127t[tid] = cv; s127t[tid] = sv;
        } else if (tid >= 128 && tid < 254) {
            const int m = tid - 128;
            float sv, cv; __sincosf((float)m * w126, &sv, &cv);
            c126t[m] = cv; s126t[m] = sv;
        }
        __syncthreads();
        if (tid < 64) {
            const int k = tid;
            float a = 0.f, bq = 0.f;
            int r = 0;
            for (int m = 0; m < 127; ++m) {
                a  += zl[m] * c127t[r];
                bq -= zl[m] * s127t[r];
                r += k; if (r >= 127) r -= 127;
            }
            ZA[k] = a; ZB[k] = bq;
        }
        __syncthreads();
        const int t = tq * 4 + (tid >> 6);
        const int j = tid & 63;
        const int jj = 63 + j;
        float acc = ZA[0];
        int rb = t, ra = jj;                       // k = 1 values
        for (int k = 1; k <= 62; ++k) {
            const float cA = c126t[rb], sA = s126t[rb];
            const float cB = c127t[ra], sB = s127t[ra];
            const float cAB = cA * cB + sA * sB;   // cos(A-B)
            const float sAB = sA * cB - cA * sB;   // sin(A-B)
            acc += 2.f * (ZA[k] * cAB - ZB[k] * sAB);
            rb += t;  if (rb >= 126) rb -= 126;
            ra += jj; if (ra >= 127) ra -= 127;
        }
        {   // Nyquist of length-126 inverse
            const int rn = (63 * jj) % 127;
            const float term = ZA[63] * c127t[rn] + ZB[63] * s127t[rn];
            acc += (t & 1) ? -term : term;
        }
        G[((size_t)h * 64 + t) * 64 + j] = acc * (1.0f / 126.0f);
    }
}

// ---------------------------------------------------------------------------
// Kernel 2:
//  bid < 512 : block (bh, tq). Phase-1 arrays {GlT, usl, vsl} and phase-2
//    arrays {rxv, rxu} now UNIONED (50.2 KiB vs 76.3 KiB -> 3 blocks/CU
//    capacity). Conv accumulates in regs; extra barrier before overwriting
//    phase-1 storage with phase-2 results.
//  bid >= 512: 64 tail blocks emit out2 from G and o_ (v4f G reads).
// ---------------------------------------------------------------------------
union K2Smem {
    struct { float GlT[64 * 68]; float usl[4096]; float vsl[4096]; } a;
    struct { float rxv[64 * 68]; float rxu[16 * 68]; } p2;
    struct { float zpb[1024]; float ol[64]; } t;
};

__global__ __launch_bounds__(256) void convemit_kernel(
        const float* __restrict__ G,
        const float* __restrict__ us,
        const float* __restrict__ vs_part,
        const float* __restrict__ ovec,
        float* __restrict__ out) {
    const int bid = blockIdx.x;
    const int tid = threadIdx.x;

    __shared__ __align__(16) K2Smem sm;

    if (bid < 512) {
        const int bh = bid >> 2, tq = bid & 3;
        const int b = bh >> 4, h = bh & 15;

        const v4f* usg = (const v4f*)(us + (size_t)bh * 4096);
        const v4f* vp0 = (const v4f*)(vs_part + (size_t)bh * 4096);
        const v4f* vp1 = (const v4f*)(vs_part + (size_t)(128 + bh) * 4096);
        const v4f* vp2 = (const v4f*)(vs_part + (size_t)(256 + bh) * 4096);
        const v4f* vp3 = (const v4f*)(vs_part + (size_t)(384 + bh) * 4096);
        const v4f* Gg  = (const v4f*)(G + (size_t)h * 4096);

#pragma unroll
        for (int k = 0; k < 4; ++k) {
            const int vi = k * 256 + tid;       // v4f index
            const int fi = vi * 4;              // float index
            v4f uu = usg[vi];
            *(v4f*)&sm.a.usl[fi] = uu;
            v4f a = (vp0[vi] + vp1[vi]) + (vp2[vi] + vp3[vi]);
            *(v4f*)&sm.a.vsl[fi] = a;
            v4f g = Gg[vi];
            const int t = fi >> 6, j0 = fi & 63;
            sm.a.GlT[(j0 + 0) * 68 + t] = g.x;
            sm.a.GlT[(j0 + 1) * 68 + t] = g.y;
            sm.a.GlT[(j0 + 2) * 68 + t] = g.z;
            sm.a.GlT[(j0 + 3) * 68 + t] = g.w;
        }
        __syncthreads();

        const int tb = tid >> 4;           // 0..15
        const int q  = tid & 15;           // e-chunk (float4)
        const int i_row = tq * 16 + tb;
        v4f accV[4];
#pragma unroll
        for (int r = 0; r < 4; ++r) accV[r] = (v4f)0.f;
        v4f accU = (v4f)0.f;
        {
            const v4f* us4 = (const v4f*)sm.a.usl;
            const v4f* vs4 = (const v4f*)sm.a.vsl;
#pragma unroll 8
            for (int j = 0; j < 64; ++j) {
                const v4f gv = *(const v4f*)&sm.a.GlT[j * 68 + tb * 4];
                const float gu = sm.a.GlT[j * 68 + i_row];
                const v4f vv = vs4[j * 16 + q];
                const v4f uu = us4[j * 16 + q];
                accV[0] += gv.x * vv;
                accV[1] += gv.y * vv;
                accV[2] += gv.z * vv;
                accV[3] += gv.w * vv;
                accU += gu * uu;
            }
        }
        __syncthreads();   // all conv reads of phase-1 storage complete
#pragma unroll
        for (int r = 0; r < 4; ++r)
            *(v4f*)&sm.p2.rxv[(tb * 4 + r) * 68 + q * 4] = accV[r];
        *(v4f*)&sm.p2.rxu[tb * 68 + q * 4] = accU;
        __syncthreads();

        // store phase: lane = (jsub 0..3, qq 0..15); each thread covers
        // j = jj*16 + w*4 + jsub (jj=0..3) and e-chunk qq, all 16 il rows.
        const int w = tid >> 6, lane = tid & 63;
        const int jsub = lane >> 4, qq = lane & 15;
        v4f rv4[4];
#pragma unroll
        for (int jj = 0; jj < 4; ++jj)
            rv4[jj] = *(const v4f*)&sm.p2.rxv[(jj * 16 + w * 4 + jsub) * 68 + qq * 4];
        const size_t obase =
            (((size_t)b * 4096 + tq * 1024) * 16 + h) * 64 + qq * 4;
        for (int il = 0; il < 16; ++il) {
            const v4f ru = *(const v4f*)&sm.p2.rxu[il * 68 + qq * 4];
#pragma unroll
            for (int jj = 0; jj < 4; ++jj) {
                const int j = jj * 16 + w * 4 + jsub;
                __builtin_nontemporal_store(rv4[jj] + ru,
                    (v4f*)(out + obase + (size_t)(il * 64 + j) * 1024));
            }
        }
    } else {
        const int bz = bid - 512;          // 0..63: the t>>6 coordinate
        if (tid < 64) sm.t.ol[tid] = ovec[tid];
        __syncthreads();
#pragma unroll
        for (int r = 0; r < 4; ++r) {
            const int idx = tid + 256 * r;
            const int h = idx >> 6, n = idx & 63;
            const v4f* G4 = (const v4f*)(G + (size_t)h * 4096 + n * 64);
            v4f acc4 = (v4f)0.f;
#pragma unroll
            for (int jv = 0; jv < 16; ++jv)
                acc4 += (*(const v4f*)&sm.t.ol[jv * 4]) * G4[jv];
            sm.t.zpb[idx] = (acc4.x + acc4.y + acc4.z + acc4.w) * 64.f;  // * s
        }
        __syncthreads();
#pragma unroll
        for (int r = 0; r < 4; ++r) {
            const int k = tid + 256 * r;
            const int hh = k & 15, c = k >> 4;
            out[OUT2_OFF + ((size_t)(bz * 64 + c)) * 16 + hh] =
                sm.t.zpb[hh * 64 + c] + sm.t.zpb[hh * 64 + bz];
        }
    }
}

extern "C" void kernel_launch(void* const* d_in, const int* in_sizes, int n_in,
                              void* d_out, int out_size, void* d_ws, size_t ws_size,
                              hipStream_t stream) {
    const float* v    = (const float*)d_in[0];   // (8,4096,16,64) f32
    const float* wgt  = (const float*)d_in[1];   // (1,16,127) f32
    const float* ovec = (const float*)d_in[2];   // (64,) f32

    float* G       = (float*)d_ws;               // 65536 floats
    float* us      = G + 65536;                  // 524288 floats
    float* vs_part = us + 524288;                // 2097152 floats
    float* out     = (float*)d_out;

    hipLaunchKernelGGL(fused1_kernel,   dim3(512 + 256), dim3(256), 0, stream,
                       v, wgt, us, vs_part, G);
    hipLaunchKernelGGL(convemit_kernel, dim3(512 + 64),  dim3(256), 0, stream,
                       G, us, vs_part, ovec, out);
}